// Round 1
// baseline (126.471 us; speedup 1.0000x reference)
//
#include <hip/hip_runtime.h>

#define N_NODES 100000
#define T_DIM 64
#define D_DIM 128
#define M_MATS 8
#define CROSS_PRUNE 0.1f

// Kernel 1: w_mat[t][d] = sum_m head_w[m] * mats[m][t][d]   (64*128 = 8192 outputs)
__global__ __launch_bounds__(256) void wmat_kernel(const float* __restrict__ mats,
                                                   const float* __restrict__ head_w,
                                                   float* __restrict__ w) {
    int i = blockIdx.x * 256 + threadIdx.x;  // 0 .. 8191
    if (i < T_DIM * D_DIM) {
        float acc = 0.f;
#pragma unroll
        for (int m = 0; m < M_MATS; ++m)
            acc += head_w[m] * mats[m * (T_DIM * D_DIM) + i];
        w[i] = acc;
    }
}

// Kernel 2: out[t][n] = prune(sigmoid(dot(w_mat[t], x[n]) + b))
// Block = 256 threads = 4 waves. Block owns 64 n-values (lane <-> n).
// Wave wv handles t in [wv*16, wv*16+16). x staged once into LDS (stride 132 pad).
// w_mat read at wave-uniform addresses -> scalar loads (s_load), scalar cache.
__global__ __launch_bounds__(256) void cross_kernel(const float* __restrict__ x,
                                                    const float* __restrict__ w,
                                                    const float* __restrict__ head_b_p,
                                                    float* __restrict__ out) {
    __shared__ float xs[64 * 132];  // 33792 B, +4 pad kills b128 bank conflicts

    const int tid = threadIdx.x;
    const int n0 = blockIdx.x * 64;

    // ---- stage x[n0 .. n0+64) into LDS, coalesced float4 ----
#pragma unroll
    for (int i = 0; i < 8; ++i) {
        int e = (i * 256 + tid) * 4;   // element index in [0, 8192)
        int row = e >> 7;              // / 128
        int col = e & 127;             // % 128
        int gn = n0 + row;
        float4 v = make_float4(0.f, 0.f, 0.f, 0.f);
        if (gn < N_NODES)
            v = *reinterpret_cast<const float4*>(x + (size_t)gn * D_DIM + col);
        *reinterpret_cast<float4*>(&xs[row * 132 + col]) = v;
    }
    __syncthreads();

    const int lane = tid & 63;
    const int wv = tid >> 6;
    const int n = n0 + lane;
    const float* __restrict__ wrow = w + wv * 16 * D_DIM;

    float acc[16];
#pragma unroll
    for (int t = 0; t < 16; ++t) acc[t] = 0.f;

    for (int kc = 0; kc < 8; ++kc) {
        const float* xp = &xs[lane * 132 + kc * 16];
        float4 x0 = *reinterpret_cast<const float4*>(xp + 0);
        float4 x1 = *reinterpret_cast<const float4*>(xp + 4);
        float4 x2 = *reinterpret_cast<const float4*>(xp + 8);
        float4 x3 = *reinterpret_cast<const float4*>(xp + 12);
#pragma unroll
        for (int t = 0; t < 16; ++t) {
            const float* wr = wrow + t * D_DIM + kc * 16;  // wave-uniform -> s_load
            float a = acc[t];
            a += wr[0]  * x0.x;  a += wr[1]  * x0.y;
            a += wr[2]  * x0.z;  a += wr[3]  * x0.w;
            a += wr[4]  * x1.x;  a += wr[5]  * x1.y;
            a += wr[6]  * x1.z;  a += wr[7]  * x1.w;
            a += wr[8]  * x2.x;  a += wr[9]  * x2.y;
            a += wr[10] * x2.z;  a += wr[11] * x2.w;
            a += wr[12] * x3.x;  a += wr[13] * x3.y;
            a += wr[14] * x3.z;  a += wr[15] * x3.w;
            acc[t] = a;
        }
    }

    const float hb = head_b_p[0];
    if (n < N_NODES) {
#pragma unroll
        for (int t = 0; t < 16; ++t) {
            float v = acc[t] + hb;
            float s = 1.0f / (1.0f + __expf(-v));
            if (s < CROSS_PRUNE) s = 0.0f;
            out[(size_t)(wv * 16 + t) * N_NODES + n] = s;
        }
    }
}

extern "C" void kernel_launch(void* const* d_in, const int* in_sizes, int n_in,
                              void* d_out, int out_size, void* d_ws, size_t ws_size,
                              hipStream_t stream) {
    const float* x      = (const float*)d_in[0];  // [N, D]
    const float* mats   = (const float*)d_in[1];  // [M, T, D]
    const float* head_w = (const float*)d_in[2];  // [M]
    const float* head_b = (const float*)d_in[3];  // [] (1 element)
    float* out = (float*)d_out;                   // [T, N]
    float* w   = (float*)d_ws;                    // [T, D] scratch, 32 KB

    hipLaunchKernelGGL(wmat_kernel, dim3((T_DIM * D_DIM + 255) / 256), dim3(256), 0, stream,
                       mats, head_w, w);

    int nchunks = (N_NODES + 63) / 64;  // 1563
    hipLaunchKernelGGL(cross_kernel, dim3(nchunks), dim3(256), 0, stream,
                       x, w, head_b, out);
}

// Round 3
// 85.750 us; speedup vs baseline: 1.4749x; 1.4749x over previous
//
#include <hip/hip_runtime.h>

#define N_NODES 100000
#define T_DIM 64
#define D_DIM 128
#define M_MATS 8
#define CROSS_PRUNE 0.1f

// ---------------- Kernel 1: wT[d][t] = sum_m head_w[m] * mats[m][t][d] ----------------
__global__ __launch_bounds__(256) void wmat_kernel(const float* __restrict__ mats,
                                                   const float* __restrict__ head_w,
                                                   float* __restrict__ wT) {
    int i = blockIdx.x * 256 + threadIdx.x;   // i = t*128 + d  (coalesced over mats)
    if (i < T_DIM * D_DIM) {
        int t = i >> 7;
        int d = i & 127;
        float acc = 0.f;
#pragma unroll
        for (int m = 0; m < M_MATS; ++m)
            acc += head_w[m] * mats[m * (T_DIM * D_DIM) + i];
        wT[d * T_DIM + t] = acc;   // transposed store (8192 elems, trivial)
    }
}

// ---------------- Kernel 2: out[t][n] = prune(sigmoid(dot(w[t], x[n]) + b)) ----------------
// Block = 256 threads (4 waves); thread <-> one n; every thread accumulates all 64 t.
// W^T addresses depend only on loop constants -> wave-uniform -> s_load (SGPR broadcast).
// x staged per 16-d chunk into LDS with stride 20 (80 B) -> conflict-free ds_read_b128.
#define XCH 16          // d-chunk size
#define XSTR 20         // LDS row stride in floats (16 + 4 pad)
__global__ __launch_bounds__(256) void cross_kernel(const float* __restrict__ x,
                                                    const float* __restrict__ wT,
                                                    const float* __restrict__ head_b_p,
                                                    float* __restrict__ out) {
    __shared__ float xs[256 * XSTR];   // 20 KB

    const int tid = threadIdx.x;
    const int n0 = blockIdx.x * 256;
    const int n = n0 + tid;

    float acc[T_DIM];
#pragma unroll
    for (int t = 0; t < T_DIM; ++t) acc[t] = 0.f;

    // staging assignment: 4 threads per row, each loads one float4 of the 16-d chunk
    const int srow = tid >> 2;          // 0..63  (row handled by this thread's quad, per wave-half? no: global)
    // NOTE: 256 threads / 4 per row = 64 rows per pass -> 4 passes cover 256 rows
    const int scol = (tid & 3) * 4;     // 0,4,8,12

    for (int ch = 0; ch < D_DIM / XCH; ++ch) {
        __syncthreads();   // protect xs from previous chunk's readers
        // ---- stage x[n0..n0+256)[ch*16 .. ch*16+16) ----
#pragma unroll
        for (int p = 0; p < 4; ++p) {
            int row = p * 64 + srow;
            int gn = n0 + row;
            float4 v = make_float4(0.f, 0.f, 0.f, 0.f);
            if (gn < N_NODES)
                v = *reinterpret_cast<const float4*>(x + (size_t)gn * D_DIM + ch * XCH + scol);
            *reinterpret_cast<float4*>(&xs[row * XSTR + scol]) = v;
        }
        __syncthreads();

        // ---- compute: 16 d-steps, 64 FMAs each, W^T via scalar loads ----
#pragma unroll
        for (int dsub = 0; dsub < 4; ++dsub) {
            float4 xv = *reinterpret_cast<const float4*>(&xs[tid * XSTR + dsub * 4]);
#pragma unroll
            for (int dd = 0; dd < 4; ++dd) {
                const int d = ch * XCH + dsub * 4 + dd;
                const float* __restrict__ wrow = wT + d * T_DIM;   // block-uniform addr
                const float xd = (dd == 0) ? xv.x : (dd == 1) ? xv.y : (dd == 2) ? xv.z : xv.w;
#pragma unroll
                for (int t = 0; t < T_DIM; ++t)
                    acc[t] = fmaf(wrow[t], xd, acc[t]);
            }
        }
    }

    // ---- epilogue ----
    const float hb = head_b_p[0];
    if (n < N_NODES) {
#pragma unroll
        for (int t = 0; t < T_DIM; ++t) {
            float v = acc[t] + hb;
            float s = 1.0f / (1.0f + __expf(-v));
            if (s < CROSS_PRUNE) s = 0.0f;
            out[(size_t)t * N_NODES + n] = s;   // per-t: 64 consecutive n per wave -> coalesced
        }
    }
}

extern "C" void kernel_launch(void* const* d_in, const int* in_sizes, int n_in,
                              void* d_out, int out_size, void* d_ws, size_t ws_size,
                              hipStream_t stream) {
    const float* x      = (const float*)d_in[0];  // [N, D]
    const float* mats   = (const float*)d_in[1];  // [M, T, D]
    const float* head_w = (const float*)d_in[2];  // [M]
    const float* head_b = (const float*)d_in[3];  // [] (1 element)
    float* out = (float*)d_out;                   // [T, N] f32
    float* wT  = (float*)d_ws;                    // [D, T] f32 scratch, 32 KB

    hipLaunchKernelGGL(wmat_kernel, dim3((T_DIM * D_DIM + 255) / 256), dim3(256), 0, stream,
                       mats, head_w, wT);

    int nblk = (N_NODES + 255) / 256;   // 391
    hipLaunchKernelGGL(cross_kernel, dim3(nblk), dim3(256), 0, stream,
                       x, wT, head_b, out);
}

// Round 4
// 51.424 us; speedup vs baseline: 2.4594x; 1.6675x over previous
//
#include <hip/hip_runtime.h>

#define N_NODES 100000
#define T_DIM 64
#define D_DIM 128
#define M_MATS 8
#define CROSS_PRUNE 0.1f

// ---------------- Kernel 1: wT[d][t] = sum_m head_w[m] * mats[m][t][d] ----------------
__global__ __launch_bounds__(256) void wmat_kernel(const float* __restrict__ mats,
                                                   const float* __restrict__ head_w,
                                                   float* __restrict__ wT) {
    int i = blockIdx.x * 256 + threadIdx.x;   // i = t*128 + d  (coalesced over mats)
    if (i < T_DIM * D_DIM) {
        int t = i >> 7;
        int d = i & 127;
        float acc = 0.f;
#pragma unroll
        for (int m = 0; m < M_MATS; ++m)
            acc += head_w[m] * mats[m * (T_DIM * D_DIM) + i];
        wT[d * T_DIM + t] = acc;   // transposed: per d, 64 t contiguous
    }
}

// ---------------- Kernel 2 ----------------
// Grid: 1563 blocks x 256 thr (4 waves). Block owns 64 n; wave wv owns t-group
// [wv*16, wv*16+16). Per thread: acc[16] (no spill). W^T read via s_load
// (readfirstlane-forced uniform base). x staged in LDS, stride 129 floats
// (coprime with 32 banks -> staging writes AND compute reads conflict-free).
#define XSTR 129
__global__ __launch_bounds__(256, 4) void cross_kernel(const float* __restrict__ x,
                                                       const float* __restrict__ wT,
                                                       const float* __restrict__ head_b_p,
                                                       float* __restrict__ out) {
    __shared__ float xs[64 * XSTR];   // 33024 B

    const int tid = threadIdx.x;
    const int n0 = blockIdx.x * 64;

    // ---- stage x[n0..n0+64)[0..128) -> LDS ----
#pragma unroll
    for (int k = 0; k < 32; ++k) {
        int e = k * 256 + tid;        // 0..8191; wave's lanes walk consecutive cols
        int row = e >> 7;
        int col = e & 127;
        int gn = n0 + row;
        float v = 0.f;
        if (gn < N_NODES) v = x[(size_t)gn * D_DIM + col];
        xs[row * XSTR + col] = v;
    }
    __syncthreads();

    const int lane = tid & 63;
    const int tg = __builtin_amdgcn_readfirstlane(tid >> 6);  // force SGPR -> s_load below
    const float* __restrict__ wbase = wT + tg * 16;           // + d*64 per step

    float acc[16];
#pragma unroll
    for (int i = 0; i < 16; ++i) acc[i] = 0.f;

#pragma unroll 4
    for (int d = 0; d < D_DIM; ++d) {
        float xd = xs[lane * XSTR + d];
        const float* __restrict__ wr = wbase + d * T_DIM;     // SGPR-uniform address
#pragma unroll
        for (int i = 0; i < 16; ++i)
            acc[i] = fmaf(wr[i], xd, acc[i]);
    }

    // ---- epilogue: sigmoid + prune + store ----
    const float hb = head_b_p[0];
    const int n = n0 + lane;
    if (n < N_NODES) {
#pragma unroll
        for (int i = 0; i < 16; ++i) {
            float v = acc[i] + hb;
            float s = 1.0f / (1.0f + __expf(-v));
            if (s < CROSS_PRUNE) s = 0.0f;
            out[(size_t)(tg * 16 + i) * N_NODES + n] = s;     // 64 consecutive n per wave
        }
    }
}

extern "C" void kernel_launch(void* const* d_in, const int* in_sizes, int n_in,
                              void* d_out, int out_size, void* d_ws, size_t ws_size,
                              hipStream_t stream) {
    const float* x      = (const float*)d_in[0];  // [N, D]
    const float* mats   = (const float*)d_in[1];  // [M, T, D]
    const float* head_w = (const float*)d_in[2];  // [M]
    const float* head_b = (const float*)d_in[3];  // [] (1 element)
    float* out = (float*)d_out;                   // [T, N] f32
    float* wT  = (float*)d_ws;                    // [D, T] f32 scratch, 32 KB

    hipLaunchKernelGGL(wmat_kernel, dim3((T_DIM * D_DIM + 255) / 256), dim3(256), 0, stream,
                       mats, head_w, wT);

    int nblk = (N_NODES + 63) / 64;   // 1563
    hipLaunchKernelGGL(cross_kernel, dim3(nblk), dim3(256), 0, stream,
                       x, wT, head_b, out);
}

// Round 5
// 35.588 us; speedup vs baseline: 3.5537x; 1.4450x over previous
//
#include <hip/hip_runtime.h>

#define N_NODES 100000
#define T_DIM 64
#define D_DIM 128
#define M_MATS 8
#define CROSS_PRUNE 0.1f

typedef __attribute__((ext_vector_type(8))) short bf16x8;   // MFMA A/B fragment
typedef __attribute__((ext_vector_type(4))) float f32x4;    // MFMA accumulator

__device__ __forceinline__ unsigned short f2bf(float f) {   // RNE f32->bf16
    unsigned int u = __float_as_uint(f);
    u += 0x7FFFu + ((u >> 16) & 1u);
    return (unsigned short)(u >> 16);
}
__device__ __forceinline__ float bf2f(unsigned short h) {
    return __uint_as_float(((unsigned int)h) << 16);
}

// ---------------- Kernel 1: w[t][d] = sum_m head_w[m] * mats[m][t][d]  (f32) ----------------
__global__ __launch_bounds__(256) void wmat_kernel(const float* __restrict__ mats,
                                                   const float* __restrict__ head_w,
                                                   float* __restrict__ w) {
    int i = blockIdx.x * 256 + threadIdx.x;
    if (i < T_DIM * D_DIM) {
        float acc = 0.f;
#pragma unroll
        for (int m = 0; m < M_MATS; ++m)
            acc += head_w[m] * mats[m * (T_DIM * D_DIM) + i];
        w[i] = acc;   // row-major [t][d]
    }
}

// ---------------- Kernel 2: 3-level bf16-split MFMA GEMM + sigmoid + prune ----------------
// Block: 256 thr (4 waves) owns 64 n. Wave tg owns t in [tg*16, tg*16+16).
// x split hi/mid/lo bf16 into LDS per 64-d half (stride 72: writes 4/bank, reads 8/bank = floor).
// W f32 loaded per-lane once per half, split in-reg -> A fragments. 6 MFMA products/ktile:
// hh + hm + mh + hl + lh + mm  (dropped terms <= 2^-26 rel -> z-err ~1e-7, f32 class).
#define HSTR 72
__global__ __launch_bounds__(256, 4) void cross_kernel(const float* __restrict__ x,
                                                       const float* __restrict__ w,
                                                       const float* __restrict__ head_b_p,
                                                       float* __restrict__ out) {
    __shared__ unsigned short xh[64 * HSTR];
    __shared__ unsigned short xm[64 * HSTR];
    __shared__ unsigned short xl[64 * HSTR];

    const int tid = threadIdx.x;
    const int n0 = blockIdx.x * 64;

    // ---- stage: thread -> (row = tid>>2, 16 cols at (tid&3)*16) per half ----
    const int srow = tid >> 2;
    const int scol = (tid & 3) * 16;
    const int gn_s = n0 + srow;
    const float* xrow = x + (size_t)gn_s * D_DIM + scol;

    float4 p0[4], p1[4];
#pragma unroll
    for (int j = 0; j < 4; ++j) {
        p0[j] = make_float4(0.f, 0.f, 0.f, 0.f);
        p1[j] = p0[j];
        if (gn_s < N_NODES) {
            p0[j] = *reinterpret_cast<const float4*>(xrow + j * 4);        // half 0
            p1[j] = *reinterpret_cast<const float4*>(xrow + 64 + j * 4);   // half 1 (prefetch)
        }
    }

    // split-store one float4 into the three LDS planes at elem offset eo
#define SPLIT_STORE(P, EO)                                                     \
    {                                                                          \
        float fv[4] = {(P).x, (P).y, (P).z, (P).w};                            \
        ushort4 H, M, L;                                                       \
        unsigned short* Hp = &H.x; unsigned short* Mp = &M.x;                  \
        unsigned short* Lp = &L.x;                                             \
        _Pragma("unroll")                                                      \
        for (int e = 0; e < 4; ++e) {                                          \
            unsigned short h_ = f2bf(fv[e]); float r1_ = fv[e] - bf2f(h_);     \
            unsigned short m_ = f2bf(r1_);   float r2_ = r1_ - bf2f(m_);      \
            Hp[e] = h_; Mp[e] = m_; Lp[e] = f2bf(r2_);                         \
        }                                                                      \
        *reinterpret_cast<ushort4*>(&xh[EO]) = H;                              \
        *reinterpret_cast<ushort4*>(&xm[EO]) = M;                              \
        *reinterpret_cast<ushort4*>(&xl[EO]) = L;                              \
    }

#pragma unroll
    for (int j = 0; j < 4; ++j)
        SPLIT_STORE(p0[j], srow * HSTR + scol + j * 4);
    __syncthreads();

    const int lane = tid & 63;
    const int tg = tid >> 6;
    const int r = lane & 15;    // A row / B col within 16
    const int q = lane >> 4;    // k sub-block / C row group

    f32x4 acc[4];
#pragma unroll
    for (int nt = 0; nt < 4; ++nt) acc[nt] = (f32x4){0.f, 0.f, 0.f, 0.f};

#pragma unroll
    for (int half = 0; half < 2; ++half) {
        if (half == 1) {
            __syncthreads();   // half-0 readers done
#pragma unroll
            for (int j = 0; j < 4; ++j)
                SPLIT_STORE(p1[j], srow * HSTR + scol + j * 4);
            __syncthreads();
        }

        // ---- A fragments: W[tg*16+r][half*64 + k4*32 + q*8 + 0..8), split 3-ways ----
        bf16x8 ah[2], am[2], al[2];
#pragma unroll
        for (int k4 = 0; k4 < 2; ++k4) {
            const float* wp = w + (tg * 16 + r) * D_DIM + half * 64 + k4 * 32 + q * 8;
            float4 wa = *reinterpret_cast<const float4*>(wp);
            float4 wb = *reinterpret_cast<const float4*>(wp + 4);
            float wf[8] = {wa.x, wa.y, wa.z, wa.w, wb.x, wb.y, wb.z, wb.w};
#pragma unroll
            for (int j = 0; j < 8; ++j) {
                unsigned short h_ = f2bf(wf[j]); float r1_ = wf[j] - bf2f(h_);
                unsigned short m_ = f2bf(r1_);   float r2_ = r1_ - bf2f(m_);
                ah[k4][j] = (short)h_; am[k4][j] = (short)m_; al[k4][j] = (short)f2bf(r2_);
            }
        }

        // ---- 6-product MFMA accumulation ----
#pragma unroll
        for (int k4 = 0; k4 < 2; ++k4) {
#pragma unroll
            for (int nt = 0; nt < 4; ++nt) {
                int eo = (nt * 16 + r) * HSTR + k4 * 32 + q * 8;
                bf16x8 bh = *reinterpret_cast<const bf16x8*>(&xh[eo]);
                bf16x8 bm = *reinterpret_cast<const bf16x8*>(&xm[eo]);
                bf16x8 bl = *reinterpret_cast<const bf16x8*>(&xl[eo]);
                acc[nt] = __builtin_amdgcn_mfma_f32_16x16x32_bf16(ah[k4], bh, acc[nt], 0, 0, 0);
                acc[nt] = __builtin_amdgcn_mfma_f32_16x16x32_bf16(ah[k4], bm, acc[nt], 0, 0, 0);
                acc[nt] = __builtin_amdgcn_mfma_f32_16x16x32_bf16(am[k4], bh, acc[nt], 0, 0, 0);
                acc[nt] = __builtin_amdgcn_mfma_f32_16x16x32_bf16(ah[k4], bl, acc[nt], 0, 0, 0);
                acc[nt] = __builtin_amdgcn_mfma_f32_16x16x32_bf16(al[k4], bh, acc[nt], 0, 0, 0);
                acc[nt] = __builtin_amdgcn_mfma_f32_16x16x32_bf16(am[k4], bm, acc[nt], 0, 0, 0);
            }
        }
    }

    // ---- epilogue: sigmoid + prune + store (C: col=lane&15 -> n, row=q*4+i -> t) ----
    const float hb = head_b_p[0];
#pragma unroll
    for (int nt = 0; nt < 4; ++nt) {
        int n = n0 + nt * 16 + r;
        if (n < N_NODES) {
#pragma unroll
            for (int i = 0; i < 4; ++i) {
                int t = tg * 16 + q * 4 + i;
                float v = acc[nt][i] + hb;
                float s = 1.0f / (1.0f + __expf(-v));
                if (s < CROSS_PRUNE) s = 0.0f;
                out[(size_t)t * N_NODES + n] = s;
            }
        }
    }
#undef SPLIT_STORE
}

extern "C" void kernel_launch(void* const* d_in, const int* in_sizes, int n_in,
                              void* d_out, int out_size, void* d_ws, size_t ws_size,
                              hipStream_t stream) {
    const float* x      = (const float*)d_in[0];  // [N, D]
    const float* mats   = (const float*)d_in[1];  // [M, T, D]
    const float* head_w = (const float*)d_in[2];  // [M]
    const float* head_b = (const float*)d_in[3];  // [] (1 element)
    float* out = (float*)d_out;                   // [T, N] f32
    float* w   = (float*)d_ws;                    // [T, D] f32 scratch, 32 KB

    hipLaunchKernelGGL(wmat_kernel, dim3((T_DIM * D_DIM + 255) / 256), dim3(256), 0, stream,
                       mats, head_w, w);

    int nblk = (N_NODES + 63) / 64;   // 1563
    hipLaunchKernelGGL(cross_kernel, dim3(nblk), dim3(256), 0, stream,
                       x, w, head_b, out);
}

// Round 6
// 31.986 us; speedup vs baseline: 3.9539x; 1.1126x over previous
//
#include <hip/hip_runtime.h>
#include <hip/hip_bf16.h>

#define N_NODES 100000
#define T_DIM 64
#define D_DIM 128
#define M_MATS 8
#define CROSS_PRUNE 0.1f

typedef __attribute__((ext_vector_type(8))) short bf16x8;    // MFMA A/B fragment
typedef __attribute__((ext_vector_type(4))) float f32x4;     // MFMA accumulator
typedef __attribute__((ext_vector_type(8))) unsigned short ushort8;

// RNE 3-level split via native casts -> compiler emits v_cvt_pk_bf16_f32 pairs.
// Sterbenz: r1 = v - bf(v) and r2 = r1 - bf(r1) are exact in f32.
__device__ __forceinline__ void split3(float v, unsigned short& h,
                                       unsigned short& m, unsigned short& l) {
    __hip_bfloat16 bh = __float2bfloat16(v);
    float fh = __bfloat162float(bh);
    float r1 = v - fh;
    __hip_bfloat16 bm = __float2bfloat16(r1);
    float fm = __bfloat162float(bm);
    float r2 = r1 - fm;
    __hip_bfloat16 bl = __float2bfloat16(r2);
    h = __builtin_bit_cast(unsigned short, bh);
    m = __builtin_bit_cast(unsigned short, bm);
    l = __builtin_bit_cast(unsigned short, bl);
}

// ---------------- Kernel 1: w[t][d] = sum_m head_w[m] * mats[m][t][d]  (f32) ----------------
__global__ __launch_bounds__(256) void wmat_kernel(const float* __restrict__ mats,
                                                   const float* __restrict__ head_w,
                                                   float* __restrict__ w) {
    int i = blockIdx.x * 256 + threadIdx.x;
    if (i < T_DIM * D_DIM) {
        float acc = 0.f;
#pragma unroll
        for (int m = 0; m < M_MATS; ++m)
            acc += head_w[m] * mats[m * (T_DIM * D_DIM) + i];
        w[i] = acc;
    }
}

// ---------------- Kernel 2: 3-level bf16-split MFMA GEMM + sigmoid + prune ----------------
// Block: 256 thr (4 waves) owns 64 n. Wave tg owns t in [tg*16, tg*16+16).
// x split hi/mid/lo bf16 into 3 LDS planes [64 rows][64 cols] per 64-d half,
// XOR-swizzled (byte ^= (row&7)<<4): ushort8 writes AND b128 reads at the
// 8-access/bank floor. LDS total 24 KB -> 5+ blocks/CU.
__global__ __launch_bounds__(256, 5) void cross_kernel(const float* __restrict__ x,
                                                       const float* __restrict__ w,
                                                       const float* __restrict__ head_b_p,
                                                       float* __restrict__ out) {
    __shared__ unsigned short xh[64 * 64];
    __shared__ unsigned short xm[64 * 64];
    __shared__ unsigned short xl[64 * 64];

    const int tid = threadIdx.x;
    const int n0 = blockIdx.x * 64;

    // ---- global loads: thread -> (row = tid>>2, cols (tid&3)*16 .. +16) for BOTH halves ----
    const int srow = tid >> 2;
    const int scol = (tid & 3) * 16;
    const int gn_s = n0 + srow;
    const float* xrow = x + (size_t)gn_s * D_DIM + scol;

    float4 p0[4], p1[4];
#pragma unroll
    for (int j = 0; j < 4; ++j) {
        p0[j] = make_float4(0.f, 0.f, 0.f, 0.f);
        p1[j] = p0[j];
        if (gn_s < N_NODES) {
            p0[j] = *reinterpret_cast<const float4*>(xrow + j * 4);        // half 0
            p1[j] = *reinterpret_cast<const float4*>(xrow + 64 + j * 4);   // half 1
        }
    }

    // split 16 elems (4 float4) and store as 2 swizzled ushort8 per plane
#define SPLIT_STORE16(P)                                                        \
    {                                                                           \
        float fv[16];                                                           \
        _Pragma("unroll")                                                       \
        for (int j = 0; j < 4; ++j) {                                           \
            fv[j * 4 + 0] = (P)[j].x; fv[j * 4 + 1] = (P)[j].y;                 \
            fv[j * 4 + 2] = (P)[j].z; fv[j * 4 + 3] = (P)[j].w;                 \
        }                                                                       \
        _Pragma("unroll")                                                       \
        for (int u = 0; u < 2; ++u) {                                           \
            ushort8 H, M, L;                                                    \
            _Pragma("unroll")                                                   \
            for (int e = 0; e < 8; ++e) {                                       \
                unsigned short h_, m_, l_;                                      \
                split3(fv[u * 8 + e], h_, m_, l_);                              \
                H[e] = h_; M[e] = m_; L[e] = l_;                                \
            }                                                                   \
            int unit = srow * 8 + (tid & 3) * 2 + u;                            \
            int byte = (unit << 4) ^ ((srow & 7) << 4);                         \
            *reinterpret_cast<ushort8*>(reinterpret_cast<char*>(xh) + byte) = H;\
            *reinterpret_cast<ushort8*>(reinterpret_cast<char*>(xm) + byte) = M;\
            *reinterpret_cast<ushort8*>(reinterpret_cast<char*>(xl) + byte) = L;\
        }                                                                       \
    }

    SPLIT_STORE16(p0);
    __syncthreads();

    const int lane = tid & 63;
    const int tg = tid >> 6;
    const int r = lane & 15;    // A row / B col within 16
    const int q = lane >> 4;    // k sub-block / C row group

    f32x4 acc[4];
#pragma unroll
    for (int nt = 0; nt < 4; ++nt) acc[nt] = (f32x4){0.f, 0.f, 0.f, 0.f};

#pragma unroll
    for (int half = 0; half < 2; ++half) {
        if (half == 1) {
            __syncthreads();   // half-0 readers done
            SPLIT_STORE16(p1);
            __syncthreads();
        }

        // ---- A fragments: W[tg*16+r][half*64 + k4*32 + q*8 .. +8), split 3-ways ----
        bf16x8 ah[2], am[2], al[2];
#pragma unroll
        for (int k4 = 0; k4 < 2; ++k4) {
            const float* wp = w + (tg * 16 + r) * D_DIM + half * 64 + k4 * 32 + q * 8;
            float4 wa = *reinterpret_cast<const float4*>(wp);
            float4 wb = *reinterpret_cast<const float4*>(wp + 4);
            float wf[8] = {wa.x, wa.y, wa.z, wa.w, wb.x, wb.y, wb.z, wb.w};
#pragma unroll
            for (int j = 0; j < 8; ++j) {
                unsigned short h_, m_, l_;
                split3(wf[j], h_, m_, l_);
                ah[k4][j] = (short)h_; am[k4][j] = (short)m_; al[k4][j] = (short)l_;
            }
        }

        // ---- 6-product MFMA accumulation (swizzled b128 reads) ----
#pragma unroll
        for (int k4 = 0; k4 < 2; ++k4) {
#pragma unroll
            for (int nt = 0; nt < 4; ++nt) {
                int byte = (((nt * 16 + r) * 64 + k4 * 32 + q * 8) << 1) ^ ((r & 7) << 4);
                bf16x8 bh = *reinterpret_cast<const bf16x8*>(
                    reinterpret_cast<const char*>(xh) + byte);
                bf16x8 bm = *reinterpret_cast<const bf16x8*>(
                    reinterpret_cast<const char*>(xm) + byte);
                bf16x8 bl = *reinterpret_cast<const bf16x8*>(
                    reinterpret_cast<const char*>(xl) + byte);
                acc[nt] = __builtin_amdgcn_mfma_f32_16x16x32_bf16(ah[k4], bh, acc[nt], 0, 0, 0);
                acc[nt] = __builtin_amdgcn_mfma_f32_16x16x32_bf16(ah[k4], bm, acc[nt], 0, 0, 0);
                acc[nt] = __builtin_amdgcn_mfma_f32_16x16x32_bf16(am[k4], bh, acc[nt], 0, 0, 0);
                acc[nt] = __builtin_amdgcn_mfma_f32_16x16x32_bf16(ah[k4], bl, acc[nt], 0, 0, 0);
                acc[nt] = __builtin_amdgcn_mfma_f32_16x16x32_bf16(al[k4], bh, acc[nt], 0, 0, 0);
                acc[nt] = __builtin_amdgcn_mfma_f32_16x16x32_bf16(am[k4], bm, acc[nt], 0, 0, 0);
            }
        }
    }

    // ---- epilogue: sigmoid + prune + store (C: col=lane&15 -> n, row=q*4+i -> t) ----
    const float hb = head_b_p[0];
#pragma unroll
    for (int nt = 0; nt < 4; ++nt) {
        int n = n0 + nt * 16 + r;
        if (n < N_NODES) {
#pragma unroll
            for (int i = 0; i < 4; ++i) {
                int t = tg * 16 + q * 4 + i;
                float v = acc[nt][i] + hb;
                float s = 1.0f / (1.0f + __expf(-v));
                if (s < CROSS_PRUNE) s = 0.0f;
                out[(size_t)t * N_NODES + n] = s;
            }
        }
    }
#undef SPLIT_STORE16
}

extern "C" void kernel_launch(void* const* d_in, const int* in_sizes, int n_in,
                              void* d_out, int out_size, void* d_ws, size_t ws_size,
                              hipStream_t stream) {
    const float* x      = (const float*)d_in[0];  // [N, D]
    const float* mats   = (const float*)d_in[1];  // [M, T, D]
    const float* head_w = (const float*)d_in[2];  // [M]
    const float* head_b = (const float*)d_in[3];  // [] (1 element)
    float* out = (float*)d_out;                   // [T, N] f32
    float* w   = (float*)d_ws;                    // [T, D] f32 scratch, 32 KB

    hipLaunchKernelGGL(wmat_kernel, dim3((T_DIM * D_DIM + 255) / 256), dim3(256), 0, stream,
                       mats, head_w, w);

    int nblk = (N_NODES + 63) / 64;   // 1563
    hipLaunchKernelGGL(cross_kernel, dim3(nblk), dim3(256), 0, stream,
                       x, w, head_b, out);
}